// Round 6
// baseline (944.712 us; speedup 1.0000x reference)
//
#include <hip/hip_runtime.h>

typedef unsigned short u16;
typedef __attribute__((ext_vector_type(8))) short short8;
typedef __attribute__((ext_vector_type(4))) float f32x4;
typedef __attribute__((ext_vector_type(16))) float f32x16;

#define E_DIM 1408
#define H_HEADS 16
#define S_SEQ 1025
#define B_BATCH 8
#define S_PAD 1088      // 17*64
#define D_PAD 128
#define M_ROWS 8200     // B*S
#define M_PAD 8320      // 65*128
#define N_QKV 4224

__device__ __forceinline__ u16 f2bf(float f){
  union { float f; unsigned u; } x; x.f = f;
  unsigned r = x.u + 0x7fffu + ((x.u >> 16) & 1u);
  return (u16)(r >> 16);
}

__device__ __forceinline__ void gload16(const void* g, void* l){
  __builtin_amdgcn_global_load_lds(
      (const __attribute__((address_space(1))) void*)g,
      (__attribute__((address_space(3))) void*)l, 16, 0, 0);
}

__device__ __forceinline__ f32x4 mfma16(short8 a, short8 b, f32x4 c){
  return __builtin_amdgcn_mfma_f32_16x16x32_bf16(a, b, c, 0, 0, 0);
}
__device__ __forceinline__ f32x16 mfma32(short8 a, short8 b, f32x16 c){
  return __builtin_amdgcn_mfma_f32_32x32x16_bf16(a, b, c, 0, 0, 0);
}

__device__ __forceinline__ unsigned cvtpk(float a, float b){
  unsigned r;
  asm("v_cvt_pk_bf16_f32 %0, %1, %2" : "=v"(r) : "v"(a), "v"(b));
  return r;
}
__device__ __forceinline__ void plswap(unsigned &a, unsigned &b){
  asm("v_permlane32_swap_b32 %0, %1" : "+v"(a), "+v"(b));
}

// ---------------- fp32 -> bf16 convert (8 elems/thread) ----------------
__global__ __launch_bounds__(256) void cvt_kernel(const float* __restrict__ src,
                                                  u16* __restrict__ dst, int n8){
  int i = blockIdx.x * 256 + threadIdx.x;
  if (i >= n8) return;
  const float4* s4 = (const float4*)src;
  float4 a = s4[2*i], b = s4[2*i+1];
  union { u16 u[8]; short8 v; } o;
  o.u[0]=f2bf(a.x); o.u[1]=f2bf(a.y); o.u[2]=f2bf(a.z); o.u[3]=f2bf(a.w);
  o.u[4]=f2bf(b.x); o.u[5]=f2bf(b.y); o.u[6]=f2bf(b.z); o.u[7]=f2bf(b.w);
  ((short8*)dst)[i] = o.v;
}

// 3 equal-size weight matrices (q,k,v) in one dispatch (grid.y = 3)
__global__ __launch_bounds__(256) void cvt3_kernel(const float* __restrict__ s0,
                                                   const float* __restrict__ s1,
                                                   const float* __restrict__ s2,
                                                   u16* __restrict__ dst, int n8){
  int i = blockIdx.x * 256 + threadIdx.x;
  if (i >= n8) return;
  const float* src = (blockIdx.y == 0) ? s0 : (blockIdx.y == 1) ? s1 : s2;
  u16* d = dst + (size_t)blockIdx.y * n8 * 8;
  const float4* s4 = (const float4*)src;
  float4 a = s4[2*i], b = s4[2*i+1];
  union { u16 u[8]; short8 v; } o;
  o.u[0]=f2bf(a.x); o.u[1]=f2bf(a.y); o.u[2]=f2bf(a.z); o.u[3]=f2bf(a.w);
  o.u[4]=f2bf(b.x); o.u[5]=f2bf(b.y); o.u[6]=f2bf(b.z); o.u[7]=f2bf(b.w);
  ((short8*)d)[i] = o.v;
}

// ---------------- zero hazardous pad regions ----------------
__global__ __launch_bounds__(256) void zero_pads_kernel(u16* __restrict__ Q,
                                                        u16* __restrict__ K,
                                                        u16* __restrict__ Vt){
  int i = blockIdx.x * 256 + threadIdx.x;
  const int n1 = 128 * S_PAD * 8;
  const int n2 = 128 * 63 * 96;
  const int n3 = 128 * 96 * 63;
  if (i < n1){
    int d = 88 + (i & 7); int t = i >> 3;
    int s = t % S_PAD; int bh = t / S_PAD;
    size_t o = ((size_t)bh * S_PAD + s) * D_PAD + d;
    Q[o] = 0; K[o] = 0;
  } else if (i < n1 + n2){
    int j = i - n1;
    int d = j % 96; int t = j / 96;
    int s = 1025 + t % 63; int bh = t / 63;
    size_t o = ((size_t)bh * S_PAD + s) * D_PAD + d;
    Q[o] = 0; K[o] = 0;
  } else if (i < n1 + n2 + n3){
    int j = i - n1 - n2;
    int d = j % 96; int t = j / 96;
    int sp = 1025 + t % 63; int bh = t / 63;
    Vt[((size_t)bh * D_PAD + d) * S_PAD + sp] = 0;
  }
}

// ---------------- GEMM  C = A @ W^T + bias (m97-style 128x128) ----------------
// MODE 0: fused QKV (bx/11 = region): Q (RoPE, pre-scaled), K (RoPE), V^T
// MODE 1: fp32 out (O-projection)
template<int MODE>
__global__ __launch_bounds__(256) void gemm_bt(
    const u16* __restrict__ A, const u16* __restrict__ W,
    const float* __restrict__ b_q, const float* __restrict__ b_k,
    const float* __restrict__ b_v,
    u16* __restrict__ Qb, u16* __restrict__ Kb, u16* __restrict__ Vtb,
    float* __restrict__ outF,
    const float* __restrict__ fcos, const float* __restrict__ fsin)
{
  __shared__ u16 As[128*32];
  __shared__ u16 Bs[128*32];
  const int tid = threadIdx.x;
  const int lane = tid & 63, wid = tid >> 6;
  const int cl = lane & 15, grp = lane >> 4;

  // bijective XCD swizzle (m204)
  const int nwg = (int)(gridDim.x * gridDim.y);
  const int orig = blockIdx.x + gridDim.x * blockIdx.y;
  const int qq = nwg >> 3, rr = nwg & 7;
  const int xcd = orig & 7, kk = orig >> 3;
  const int wg = (xcd < rr ? xcd * (qq + 1) : rr * (qq + 1) + (xcd - rr) * qq) + kk;
  const int bx = wg % (int)gridDim.x, by = wg / (int)gridDim.x;

  const int n0 = bx * 128, m0 = by * 128;
  const int region = (MODE == 0) ? (bx / 11) : 0;
  const int wm = (wid >> 1) * 64, wn = (wid & 1) * 64;
  f32x4 acc[4][4] = {};

  for (int k0 = 0; k0 < E_DIM; k0 += 32){
    __syncthreads();
#pragma unroll
    for (int rd = 0; rd < 2; ++rd){
      int G = rd * 256 + tid;
      int row = G >> 2, cg = G & 3;
      gload16(A + (size_t)(m0 + row) * E_DIM + k0 + cg * 8, (char*)As + (size_t)G * 16);
      gload16(W + (size_t)(n0 + row) * E_DIM + k0 + cg * 8, (char*)Bs + (size_t)G * 16);
    }
    __syncthreads();
    short8 av[4], bv[4];
#pragma unroll
    for (int i = 0; i < 4; ++i) av[i] = *(const short8*)&As[(wm + i*16 + cl)*32 + grp*8];
#pragma unroll
    for (int j = 0; j < 4; ++j) bv[j] = *(const short8*)&Bs[(wn + j*16 + cl)*32 + grp*8];
    __builtin_amdgcn_s_setprio(1);
#pragma unroll
    for (int i = 0; i < 4; ++i)
#pragma unroll
      for (int j = 0; j < 4; ++j)
        acc[i][j] = mfma16(av[i], bv[j], acc[i][j]);
    __builtin_amdgcn_s_setprio(0);
  }

  const float* bias = (MODE == 1) ? b_q : (region == 0 ? b_q : (region == 1 ? b_k : b_v));
  const float QSCALE = 0.15379181f;   // log2(e)/sqrt(88), folded into Q

#pragma unroll
  for (int i = 0; i < 4; ++i){
#pragma unroll
    for (int j = 0; j < 4; ++j){
      const int jcol = n0 + wn + j*16 + cl;
      const int jl = jcol - region * E_DIM;
      const float bsv = bias[jl];
      const int hh = jl / 88;
      const int dd = jl - hh * 88;
#pragma unroll
      for (int r = 0; r < 4; ++r){
        const int rrow = m0 + wm + i*16 + grp*4 + r;
        float v = acc[i][j][r] + bsv;
        if (MODE == 0 && region <= 1){
          float other = __shfl_xor(v, 1);
          int bb = rrow / 1025;
          int spos = rrow - bb * 1025;
          int pp = dd >> 1;
          float c = fcos[spos * 44 + pp];
          float s = fsin[spos * 44 + pp];
          float o = fmaf(v, c, (jl & 1) ? (other * s) : -(other * s));
          if (region == 0) o *= QSCALE;
          if (rrow < M_ROWS){
            size_t dst = (((size_t)(bb * 16 + hh)) * S_PAD + spos) * D_PAD + dd;
            (region ? Kb : Qb)[dst] = f2bf(o);
          }
        } else if (MODE == 0){
          if (rrow < M_ROWS){
            int bb = rrow / 1025;
            int spos = rrow - bb * 1025;
            size_t dst = (((size_t)(bb * 16 + hh)) * D_PAD + dd) * S_PAD + spos;
            Vtb[dst] = f2bf(v);
          }
        } else {
          if (rrow < M_ROWS) outF[(size_t)rrow * E_DIM + jcol] = v;
        }
      }
    }
  }
}

// ---------------- fused attention (mfma 32x32x16) ----------------
// block = 256 thr (4 waves), q-tile 128. LDS (flat, 53248 B):
//   KsA: [2][64*128] u16 (32 KB, double-buffered K)
//   Vs : [96*64] u16 (12 KB)
//   Ps : per-wave [32q][32k] u16 (8 KB total) -- wave-local attn-store transpose
//   Es : overlays KsA after main loop -- [128q][96d] u16 AO-store transpose
#define STAGE_K(buf, kt)                                                        \
  {                                                                             \
    _Pragma("unroll")                                                           \
    for (int rd = 0; rd < 4; ++rd){                                             \
      int G = rd * 256 + tid;                                                   \
      int row = G >> 4, c = G & 15;                                             \
      gload16(Kg + (size_t)((kt) * 64 + row) * 128 + ((c ^ (row & 15)) * 8),    \
              (char*)(KsA + (size_t)(buf) * 8192) + (size_t)G * 16);            \
    }                                                                           \
  }

#define STAGE_V(kt)                                                             \
  {                                                                             \
    _Pragma("unroll")                                                           \
    for (int rd = 0; rd < 3; ++rd){                                             \
      int G = rd * 256 + tid;                                                   \
      int row = G >> 3, c = G & 7;                                              \
      gload16(Vg + (size_t)row * S_PAD + (kt) * 64 + ((c ^ (row & 7)) * 8),     \
              (char*)Vs + (size_t)G * 16);                                      \
    }                                                                           \
  }

__global__ __launch_bounds__(256, 3) void attn_kernel(
    const u16* __restrict__ Qb, const u16* __restrict__ Kb,
    const u16* __restrict__ Vtb, float* __restrict__ attn,
    u16* __restrict__ AO)
{
  __shared__ u16 sm[26624];
  const int tid = threadIdx.x, wid = tid >> 6, lane = tid & 63;
  u16* const KsA = sm;                       // [2][8192]
  u16* const Vs  = sm + 16384;               // [6144]
  u16* const Ps  = sm + 22528 + wid * 1024;  // [32*32] per wave
  const int q5 = lane & 31, hi = lane >> 5;
  int lin = blockIdx.x + gridDim.x * blockIdx.y;     // 9*128 = 1152 blocks
  lin = (lin & 7) * 144 + (lin >> 3);                // XCD-contiguous (1152 = 8*144)
  const int qt = lin % 9, bh = lin / 9;
  const int b = bh >> 4, h = bh & 15;
  const u16* __restrict__ Qg = Qb + (size_t)bh * S_PAD * 128;
  const u16* __restrict__ Kg = Kb + (size_t)bh * S_PAD * 128;
  const u16* __restrict__ Vg = Vtb + (size_t)bh * 128 * S_PAD;
  const int qb0 = qt * 128 + wid * 32;
  const int qrow = qb0 + q5;
  const int qrowc = (qrow < S_PAD) ? qrow : (S_PAD - 1);

  short8 qf[6];
#pragma unroll
  for (int ds = 0; ds < 6; ++ds)
    qf[ds] = *(const short8*)&Qg[(size_t)qrowc * 128 + ds * 16 + hi * 8];

  // ---- pass 1: row sums of 2^sc (pad K rows give 2^0 = 1 -> subtract 63) ----
  float l0 = 0.f, l1 = 0.f, l2 = 0.f, l3 = 0.f;
  STAGE_K(0, 0);
  __syncthreads();
  for (int kt = 0; kt < 17; ++kt){
    const int cur = kt & 1;
    if (kt < 16) STAGE_K(cur ^ 1, kt + 1);
#pragma unroll
    for (int ks = 0; ks < 2; ++ks){
      f32x16 sc = {};
      const int krow = ks * 32 + q5;
      __builtin_amdgcn_s_setprio(1);
#pragma unroll
      for (int ds = 0; ds < 6; ++ds){
        int c = ds * 2 + hi;
        short8 kf = *(const short8*)&KsA[(size_t)cur * 8192 + krow * 128 + ((c ^ (krow & 15)) * 8)];
        sc = mfma32(kf, qf[ds], sc);
      }
      __builtin_amdgcn_s_setprio(0);
#pragma unroll
      for (int r = 0; r < 16; r += 4){
        l0 += __builtin_amdgcn_exp2f(sc[r]);
        l1 += __builtin_amdgcn_exp2f(sc[r+1]);
        l2 += __builtin_amdgcn_exp2f(sc[r+2]);
        l3 += __builtin_amdgcn_exp2f(sc[r+3]);
      }
    }
    __syncthreads();
  }
  float l = (l0 + l1) + (l2 + l3);
  l += __shfl_xor(l, 32);
  l -= 63.0f;                                        // exact pad correction
  const float lg2l = __builtin_amdgcn_logf(l);

  // ---- pass 2: p = 2^(sc - lg2l); transpose-store attn; PV ----
  f32x16 oacc[3] = {};
  STAGE_K(0, 0);
  STAGE_V(0);
  __syncthreads();
  for (int kt = 0; kt < 17; ++kt){
    const int cur = kt & 1;
    if (kt < 16) STAGE_K(cur ^ 1, kt + 1);
    short8 pa0[2], pa1[2];
#pragma unroll
    for (int ks = 0; ks < 2; ++ks){
      f32x16 sc = {};
      const int krow = ks * 32 + q5;
      __builtin_amdgcn_s_setprio(1);
#pragma unroll
      for (int ds = 0; ds < 6; ++ds){
        int c = ds * 2 + hi;
        short8 kf = *(const short8*)&KsA[(size_t)cur * 8192 + krow * 128 + ((c ^ (krow & 15)) * 8)];
        sc = mfma32(kf, qf[ds], sc);
      }
      __builtin_amdgcn_s_setprio(0);
#pragma unroll
      for (int r = 0; r < 16; ++r) sc[r] = __builtin_amdgcn_exp2f(sc[r] - lg2l);

      // P -> bf16 A-fragments: 8 cvt_pk + 4 permlane32_swap
      unsigned w0 = cvtpk(sc[0],  sc[1]),  w1 = cvtpk(sc[2],  sc[3]);
      unsigned w2 = cvtpk(sc[4],  sc[5]),  w3 = cvtpk(sc[6],  sc[7]);
      unsigned w4 = cvtpk(sc[8],  sc[9]),  w5 = cvtpk(sc[10], sc[11]);
      unsigned w6 = cvtpk(sc[12], sc[13]), w7 = cvtpk(sc[14], sc[15]);
      plswap(w0, w2); plswap(w1, w3); plswap(w4, w6); plswap(w5, w7);
      union U { unsigned u[4]; short8 s8; } A0, A1;
      A0.u[0] = w0; A0.u[1] = w1; A0.u[2] = w2; A0.u[3] = w3;
      A1.u[0] = w4; A1.u[1] = w5; A1.u[2] = w6; A1.u[3] = w7;
      pa0[ks] = A0.s8; pa1[ks] = A1.s8;

      // wave-local transpose: Ps[q][k_local] = p (bf16), then lane = k store
      *(short8*)&Ps[q5 * 32 + hi * 8]      = pa0[ks];
      *(short8*)&Ps[q5 * 32 + 16 + hi * 8] = pa1[ks];
      const int kcol = kt * 64 + ks * 32 + q5;
      const bool kok = (kt < 16) || (ks == 0 && q5 == 0);   // k = 1024 only on last tile
      float* arow = attn + ((size_t)bh * 1025 + qb0) * 1025 + kcol;
#pragma unroll
      for (int p = 0; p < 16; ++p){
        const int qr2 = qb0 + 2 * p + hi;
        u16 pv = Ps[(2 * p + hi) * 32 + q5];
        if (kok && qr2 < 1025)
          arow[(size_t)(2 * p + hi) * 1025] = __uint_as_float((unsigned)pv << 16);
      }
    }

    __syncthreads();                 // V(kt) staged, all QK reads of Ks done
    __builtin_amdgcn_s_setprio(1);
#pragma unroll
    for (int ks = 0; ks < 2; ++ks){
#pragma unroll
      for (int dt = 0; dt < 3; ++dt){
        const int vrow = dt * 32 + q5;
        int c0 = ks * 4 + hi;
        short8 vf0 = *(const short8*)&Vs[vrow * 64 + ((c0 ^ (vrow & 7)) * 8)];
        oacc[dt] = mfma32(pa0[ks], vf0, oacc[dt]);
        int c1 = ks * 4 + 2 + hi;
        short8 vf1 = *(const short8*)&Vs[vrow * 64 + ((c1 ^ (vrow & 7)) * 8)];
        oacc[dt] = mfma32(pa1[ks], vf1, oacc[dt]);
      }
    }
    __builtin_amdgcn_s_setprio(0);
    __syncthreads();                 // all PV reads of Vs done
    if (kt < 16) STAGE_V(kt + 1);
  }

  // ---- AO epilogue: transpose via Es (overlays KsA), aligned short8 stores ----
  u16* const Es = sm;                // [128][96]
#pragma unroll
  for (int dt = 0; dt < 3; ++dt){
    const int d = dt * 32 + q5;
#pragma unroll
    for (int r = 0; r < 16; ++r){
      const int ql = wid * 32 + (r & 3) + 8 * (r >> 2) + 4 * hi;
      Es[ql * 96 + d] = f2bf(oacc[dt][r]);
    }
  }
  __syncthreads();
  const int qt128 = qt * 128;
  for (int c = tid; c < 1408; c += 256){
    const int row = c / 11;
    const int off = c - row * 11;
    const int qr = qt128 + row;
    if (qr < 1025){
      short8 v = *(const short8*)&Es[row * 96 + off * 8];
      *(short8*)&AO[((size_t)b * 1025 + qr) * E_DIM + h * 88 + off * 8] = v;
    }
  }
}

extern "C" void kernel_launch(void* const* d_in, const int* in_sizes, int n_in,
                              void* d_out, int out_size, void* d_ws, size_t ws_size,
                              hipStream_t stream)
{
  const float* hs   = (const float*)d_in[0];
  const float* fcos = (const float*)d_in[1];
  const float* fsin = (const float*)d_in[2];
  const float* q_w  = (const float*)d_in[3];
  const float* q_b  = (const float*)d_in[4];
  const float* k_w  = (const float*)d_in[5];
  const float* k_b  = (const float*)d_in[6];
  const float* v_w  = (const float*)d_in[7];
  const float* v_b  = (const float*)d_in[8];
  const float* o_w  = (const float*)d_in[9];
  const float* o_b  = (const float*)d_in[10];
  float* out0 = (float*)d_out;
  float* attn = out0 + (size_t)B_BATCH * S_SEQ * E_DIM;

  char* ws = (char*)d_ws;
  size_t off = 0;
  auto take = [&](size_t bytes){
    char* p = ws + off; off += (bytes + 255) & ~(size_t)255; return p;
  };
  u16* Xb   = (u16*)take((size_t)M_PAD * E_DIM * 2);
  u16* Wqkv = (u16*)take((size_t)N_QKV * E_DIM * 2);
  u16* Wo   = (u16*)take((size_t)E_DIM * E_DIM * 2);
  u16* Qb   = (u16*)take((size_t)128 * S_PAD * D_PAD * 2);
  u16* Kb   = (u16*)take((size_t)128 * S_PAD * D_PAD * 2);
  u16* Vtb  = (u16*)take((size_t)128 * D_PAD * S_PAD * 2);
  u16* AO   = (u16*)take((size_t)M_PAD * E_DIM * 2);

  cvt_kernel<<<(1443200 + 255) / 256, 256, 0, stream>>>(hs, Xb, 1443200);
  cvt3_kernel<<<dim3(968, 3), 256, 0, stream>>>(q_w, k_w, v_w, Wqkv, 247808);
  cvt_kernel<<<968, 256, 0, stream>>>(o_w, Wo, 247808);
  zero_pads_kernel<<<10400, 256, 0, stream>>>(Qb, Kb, Vtb);

  gemm_bt<0><<<dim3(33, 65), 256, 0, stream>>>(Xb, Wqkv, q_b, k_b, v_b,
                                               Qb, Kb, Vtb, nullptr, fcos, fsin);

  attn_kernel<<<dim3(9, 128), 256, 0, stream>>>(Qb, Kb, Vtb, attn, AO);

  gemm_bt<1><<<dim3(11, 65), 256, 0, stream>>>(AO, Wo, o_b, o_b, o_b,
                                               nullptr, nullptr, nullptr, out0, fcos, fsin);
}

// Round 7
// 561.301 us; speedup vs baseline: 1.6831x; 1.6831x over previous
//
#include <hip/hip_runtime.h>

typedef unsigned short u16;
typedef __attribute__((ext_vector_type(8))) short short8;
typedef __attribute__((ext_vector_type(4))) float f32x4;
typedef __attribute__((ext_vector_type(16))) float f32x16;

#define E_DIM 1408
#define H_HEADS 16
#define S_SEQ 1025
#define B_BATCH 8
#define S_PAD 1088      // 17*64
#define D_PAD 128
#define M_ROWS 8200     // B*S
#define M_PAD 8320      // 65*128
#define N_QKV 4224

struct __attribute__((packed, aligned(4))) f4u { float x, y, z, w; };

__device__ __forceinline__ u16 f2bf(float f){
  union { float f; unsigned u; } x; x.f = f;
  unsigned r = x.u + 0x7fffu + ((x.u >> 16) & 1u);
  return (u16)(r >> 16);
}

__device__ __forceinline__ void gload16(const void* g, void* l){
  __builtin_amdgcn_global_load_lds(
      (const __attribute__((address_space(1))) void*)g,
      (__attribute__((address_space(3))) void*)l, 16, 0, 0);
}

__device__ __forceinline__ f32x4 mfma16(short8 a, short8 b, f32x4 c){
  return __builtin_amdgcn_mfma_f32_16x16x32_bf16(a, b, c, 0, 0, 0);
}
__device__ __forceinline__ f32x16 mfma32(short8 a, short8 b, f32x16 c){
  return __builtin_amdgcn_mfma_f32_32x32x16_bf16(a, b, c, 0, 0, 0);
}

__device__ __forceinline__ unsigned cvtpk(float a, float b){
  unsigned r;
  asm("v_cvt_pk_bf16_f32 %0, %1, %2" : "=v"(r) : "v"(a), "v"(b));
  return r;
}
__device__ __forceinline__ void plswap(unsigned &a, unsigned &b){
  asm("v_permlane32_swap_b32 %0, %1" : "+v"(a), "+v"(b));
}

#define BARX() { asm volatile("" ::: "memory"); __builtin_amdgcn_s_barrier(); asm volatile("" ::: "memory"); }
#define WAITV(n) asm volatile("s_waitcnt vmcnt(" #n ")" ::: "memory")

// ---------------- fp32 -> bf16 convert (8 elems/thread) ----------------
__global__ __launch_bounds__(256) void cvt_kernel(const float* __restrict__ src,
                                                  u16* __restrict__ dst, int n8){
  int i = blockIdx.x * 256 + threadIdx.x;
  if (i >= n8) return;
  const float4* s4 = (const float4*)src;
  float4 a = s4[2*i], b = s4[2*i+1];
  union { u16 u[8]; short8 v; } o;
  o.u[0]=f2bf(a.x); o.u[1]=f2bf(a.y); o.u[2]=f2bf(a.z); o.u[3]=f2bf(a.w);
  o.u[4]=f2bf(b.x); o.u[5]=f2bf(b.y); o.u[6]=f2bf(b.z); o.u[7]=f2bf(b.w);
  ((short8*)dst)[i] = o.v;
}

// 3 equal-size weight matrices (q,k,v) in one dispatch (grid.y = 3)
__global__ __launch_bounds__(256) void cvt3_kernel(const float* __restrict__ s0,
                                                   const float* __restrict__ s1,
                                                   const float* __restrict__ s2,
                                                   u16* __restrict__ dst, int n8){
  int i = blockIdx.x * 256 + threadIdx.x;
  if (i >= n8) return;
  const float* src = (blockIdx.y == 0) ? s0 : (blockIdx.y == 1) ? s1 : s2;
  u16* d = dst + (size_t)blockIdx.y * n8 * 8;
  const float4* s4 = (const float4*)src;
  float4 a = s4[2*i], b = s4[2*i+1];
  union { u16 u[8]; short8 v; } o;
  o.u[0]=f2bf(a.x); o.u[1]=f2bf(a.y); o.u[2]=f2bf(a.z); o.u[3]=f2bf(a.w);
  o.u[4]=f2bf(b.x); o.u[5]=f2bf(b.y); o.u[6]=f2bf(b.z); o.u[7]=f2bf(b.w);
  ((short8*)d)[i] = o.v;
}

// ---------------- zero hazardous pad regions ----------------
__global__ __launch_bounds__(256) void zero_pads_kernel(u16* __restrict__ Q,
                                                        u16* __restrict__ K,
                                                        u16* __restrict__ Vt){
  int i = blockIdx.x * 256 + threadIdx.x;
  const int n1 = 128 * S_PAD * 8;
  const int n2 = 128 * 63 * 96;
  const int n3 = 128 * 96 * 63;
  if (i < n1){
    int d = 88 + (i & 7); int t = i >> 3;
    int s = t % S_PAD; int bh = t / S_PAD;
    size_t o = ((size_t)bh * S_PAD + s) * D_PAD + d;
    Q[o] = 0; K[o] = 0;
  } else if (i < n1 + n2){
    int j = i - n1;
    int d = j % 96; int t = j / 96;
    int s = 1025 + t % 63; int bh = t / 63;
    size_t o = ((size_t)bh * S_PAD + s) * D_PAD + d;
    Q[o] = 0; K[o] = 0;
  } else if (i < n1 + n2 + n3){
    int j = i - n1 - n2;
    int d = j % 96; int t = j / 96;
    int sp = 1025 + t % 63; int bh = t / 63;
    Vt[((size_t)bh * D_PAD + d) * S_PAD + sp] = 0;
  }
}

// ---------------- GEMM  C = A @ W^T + bias (m97-style 128x128) ----------------
// MODE 0: fused QKV (bx/11 = region): Q (RoPE, pre-scaled), K (RoPE), V^T
// MODE 1: fp32 out (O-projection)
template<int MODE>
__global__ __launch_bounds__(256) void gemm_bt(
    const u16* __restrict__ A, const u16* __restrict__ W,
    const float* __restrict__ b_q, const float* __restrict__ b_k,
    const float* __restrict__ b_v,
    u16* __restrict__ Qb, u16* __restrict__ Kb, u16* __restrict__ Vtb,
    float* __restrict__ outF,
    const float* __restrict__ fcos, const float* __restrict__ fsin)
{
  __shared__ u16 As[128*32];
  __shared__ u16 Bs[128*32];
  const int tid = threadIdx.x;
  const int lane = tid & 63, wid = tid >> 6;
  const int cl = lane & 15, grp = lane >> 4;

  // bijective XCD swizzle (m204)
  const int nwg = (int)(gridDim.x * gridDim.y);
  const int orig = blockIdx.x + gridDim.x * blockIdx.y;
  const int qq = nwg >> 3, rr = nwg & 7;
  const int xcd = orig & 7, kk = orig >> 3;
  const int wg = (xcd < rr ? xcd * (qq + 1) : rr * (qq + 1) + (xcd - rr) * qq) + kk;
  const int bx = wg % (int)gridDim.x, by = wg / (int)gridDim.x;

  const int n0 = bx * 128, m0 = by * 128;
  const int region = (MODE == 0) ? (bx / 11) : 0;
  const int wm = (wid >> 1) * 64, wn = (wid & 1) * 64;
  f32x4 acc[4][4] = {};

  for (int k0 = 0; k0 < E_DIM; k0 += 32){
    __syncthreads();
#pragma unroll
    for (int rd = 0; rd < 2; ++rd){
      int G = rd * 256 + tid;
      int row = G >> 2, cg = G & 3;
      gload16(A + (size_t)(m0 + row) * E_DIM + k0 + cg * 8, (char*)As + (size_t)G * 16);
      gload16(W + (size_t)(n0 + row) * E_DIM + k0 + cg * 8, (char*)Bs + (size_t)G * 16);
    }
    __syncthreads();
    short8 av[4], bv[4];
#pragma unroll
    for (int i = 0; i < 4; ++i) av[i] = *(const short8*)&As[(wm + i*16 + cl)*32 + grp*8];
#pragma unroll
    for (int j = 0; j < 4; ++j) bv[j] = *(const short8*)&Bs[(wn + j*16 + cl)*32 + grp*8];
    __builtin_amdgcn_s_setprio(1);
#pragma unroll
    for (int i = 0; i < 4; ++i)
#pragma unroll
      for (int j = 0; j < 4; ++j)
        acc[i][j] = mfma16(av[i], bv[j], acc[i][j]);
    __builtin_amdgcn_s_setprio(0);
  }

  const float* bias = (MODE == 1) ? b_q : (region == 0 ? b_q : (region == 1 ? b_k : b_v));
  const float QSCALE = 0.15379181f;   // log2(e)/sqrt(88), folded into Q

#pragma unroll
  for (int i = 0; i < 4; ++i){
#pragma unroll
    for (int j = 0; j < 4; ++j){
      const int jcol = n0 + wn + j*16 + cl;
      const int jl = jcol - region * E_DIM;
      const float bsv = bias[jl];
      const int hh = jl / 88;
      const int dd = jl - hh * 88;
#pragma unroll
      for (int r = 0; r < 4; ++r){
        const int rrow = m0 + wm + i*16 + grp*4 + r;
        float v = acc[i][j][r] + bsv;
        if (MODE == 0 && region <= 1){
          float other = __shfl_xor(v, 1);
          int bb = rrow / 1025;
          int spos = rrow - bb * 1025;
          int pp = dd >> 1;
          float c = fcos[spos * 44 + pp];
          float s = fsin[spos * 44 + pp];
          float o = fmaf(v, c, (jl & 1) ? (other * s) : -(other * s));
          if (region == 0) o *= QSCALE;
          if (rrow < M_ROWS){
            size_t dst = (((size_t)(bb * 16 + hh)) * S_PAD + spos) * D_PAD + dd;
            (region ? Kb : Qb)[dst] = f2bf(o);
          }
        } else if (MODE == 0){
          if (rrow < M_ROWS){
            int bb = rrow / 1025;
            int spos = rrow - bb * 1025;
            size_t dst = (((size_t)(bb * 16 + hh)) * D_PAD + dd) * S_PAD + spos;
            Vtb[dst] = f2bf(v);
          }
        } else {
          if (rrow < M_ROWS) outF[(size_t)rrow * E_DIM + jcol] = v;
        }
      }
    }
  }
}

// ---------------- fused attention (mfma 32x32x16, 8 waves, counted vmcnt) ----
// block = 512 thr (8 waves), q-tile 256: wave w owns q rows qt*256 + w*32 .. +31
// LDS 64 KB: K[2][64x128] (32 KB) + V[2][128x64] (32 KB), both double-buffered.
// Pipeline: per kt {compute; barrier; stage kt+2; vmcnt(counted); barrier} --
// next tile's loads always in flight, no vmcnt(0) drains in steady state.
#define STAGE_K(buf, kt)                                                        \
  {                                                                             \
    _Pragma("unroll")                                                           \
    for (int rd = 0; rd < 2; ++rd){                                             \
      int G = rd * 512 + tid;                                                   \
      int row = G >> 4, c = G & 15;                                             \
      gload16(Kg + (size_t)((kt) * 64 + row) * 128 + ((c ^ (row & 15)) * 8),    \
              (char*)Ks + (size_t)(buf) * 16384 + (size_t)G * 16);              \
    }                                                                           \
  }

#define STAGE_V(buf, kt)                                                        \
  {                                                                             \
    _Pragma("unroll")                                                           \
    for (int rd = 0; rd < 2; ++rd){                                             \
      int G = rd * 512 + tid;                                                   \
      int row = G >> 3, c = G & 7;                                              \
      gload16(Vg + (size_t)row * S_PAD + (kt) * 64 + ((c ^ (row & 7)) * 8),     \
              (char*)Vs + (size_t)(buf) * 16384 + (size_t)G * 16);              \
    }                                                                           \
  }

__global__ __launch_bounds__(512, 4) void attn_kernel(
    const u16* __restrict__ Qb, const u16* __restrict__ Kb,
    const u16* __restrict__ Vtb, float* __restrict__ attn,
    u16* __restrict__ AO)
{
  __shared__ u16 sm[32768];          // 64 KB
  u16* const Ks = sm;                // [2][8192]
  u16* const Vs = sm + 16384;        // [2][8192] (128 d-rows x 64 k)
  const int tid = threadIdx.x, wid = tid >> 6, lane = tid & 63;
  const int q5 = lane & 31, hi = lane >> 5;
  int lin = blockIdx.x + gridDim.x * blockIdx.y;     // 5*128 = 640 blocks
  lin = (lin & 7) * 80 + (lin >> 3);                 // XCD-contiguous (640 = 8*80)
  const int qt = lin % 5, bh = lin / 5;
  const int b = bh >> 4, h = bh & 15;
  const u16* __restrict__ Qg = Qb + (size_t)bh * S_PAD * 128;
  const u16* __restrict__ Kg = Kb + (size_t)bh * S_PAD * 128;
  const u16* __restrict__ Vg = Vtb + (size_t)bh * 128 * S_PAD;
  const int qb0 = qt * 256 + wid * 32;
  const int qrow = qb0 + q5;
  const int qrowc = (qrow < S_PAD) ? qrow : (S_PAD - 1);

  short8 qf[6];
#pragma unroll
  for (int ds = 0; ds < 6; ++ds)
    qf[ds] = *(const short8*)&Qg[(size_t)qrowc * 128 + ds * 16 + hi * 8];

  // ---- pass 1: l = sum over k of 2^sc (pad K rows give 2^0 = 1 -> -63) ----
  float l0 = 0.f, l1 = 0.f, l2 = 0.f, l3 = 0.f;
  STAGE_K(0, 0);
  STAGE_K(1, 1);
  WAITV(2);
  BARX();
  for (int kt = 0; kt < 17; ++kt){
    const int cur = kt & 1;
#pragma unroll
    for (int ks = 0; ks < 2; ++ks){
      f32x16 sc = {};
      const int krow = ks * 32 + q5;
      __builtin_amdgcn_s_setprio(1);
#pragma unroll
      for (int ds = 0; ds < 6; ++ds){
        int c = ds * 2 + hi;
        short8 kf = *(const short8*)&Ks[(size_t)cur * 8192 + krow * 128 + ((c ^ (krow & 15)) * 8)];
        sc = mfma32(kf, qf[ds], sc);
      }
      __builtin_amdgcn_s_setprio(0);
#pragma unroll
      for (int r = 0; r < 16; r += 4){
        l0 += __builtin_amdgcn_exp2f(sc[r]);
        l1 += __builtin_amdgcn_exp2f(sc[r+1]);
        l2 += __builtin_amdgcn_exp2f(sc[r+2]);
        l3 += __builtin_amdgcn_exp2f(sc[r+3]);
      }
    }
    if (kt == 16) break;
    BARX();
    if (kt <= 14){
      STAGE_K(cur, kt + 2);
      WAITV(2);                      // K[kt+1] resident; K[kt+2] in flight
    } else {                         // kt == 15: prefetch V0,V1 (V bufs idle)
      STAGE_V(0, 0);
      STAGE_V(1, 1);
      WAITV(4);                      // K[16] resident; V0,V1 in flight
    }
    BARX();
  }
  // ---- transition: restage K0,K1; reduce l ----
  BARX();
  STAGE_K(0, 0);
  STAGE_K(1, 1);
  float l = (l0 + l1) + (l2 + l3);
  l += __shfl_xor(l, 32);
  l -= 63.0f;                                        // exact pad correction
  const float lg2l = __builtin_amdgcn_logf(l);
  WAITV(2);                          // K0 + V0,V1 resident; K1 in flight
  BARX();

  // ---- pass 2: p = 2^(sc - lg2l); write attn; PV ----
  f32x16 oacc[3] = {};
  for (int kt = 0; kt < 17; ++kt){
    const int cur = kt & 1;
    short8 pa0[2], pa1[2];
#pragma unroll
    for (int ks = 0; ks < 2; ++ks){
      f32x16 sc = {};
      const int krow = ks * 32 + q5;
      __builtin_amdgcn_s_setprio(1);
#pragma unroll
      for (int ds = 0; ds < 6; ++ds){
        int c = ds * 2 + hi;
        short8 kf = *(const short8*)&Ks[(size_t)cur * 8192 + krow * 128 + ((c ^ (krow & 15)) * 8)];
        sc = mfma32(kf, qf[ds], sc);
      }
      __builtin_amdgcn_s_setprio(0);
#pragma unroll
      for (int r = 0; r < 16; ++r) sc[r] = __builtin_amdgcn_exp2f(sc[r] - lg2l);

      if (qrow < 1025){
        if (kt < 16){
          float* arow = attn + ((size_t)bh * 1025 + qrow) * 1025 + kt * 64 + ks * 32 + 4 * hi;
#pragma unroll
          for (int g = 0; g < 4; ++g){
            f4u w4 = { sc[4*g], sc[4*g+1], sc[4*g+2], sc[4*g+3] };
            *(f4u*)(arow + 8 * g) = w4;
          }
        } else {
#pragma unroll
          for (int r = 0; r < 16; ++r){
            int kabs = 1024 + ks * 32 + (r & 3) + 8 * (r >> 2) + 4 * hi;
            if (kabs < 1025)
              attn[((size_t)bh * 1025 + qrow) * 1025 + kabs] = sc[r];
          }
        }
      }

      // P -> bf16 A-fragments: 8 cvt_pk + 4 permlane32_swap
      unsigned w0 = cvtpk(sc[0],  sc[1]),  w1 = cvtpk(sc[2],  sc[3]);
      unsigned w2 = cvtpk(sc[4],  sc[5]),  w3 = cvtpk(sc[6],  sc[7]);
      unsigned w4 = cvtpk(sc[8],  sc[9]),  w5 = cvtpk(sc[10], sc[11]);
      unsigned w6 = cvtpk(sc[12], sc[13]), w7 = cvtpk(sc[14], sc[15]);
      plswap(w0, w2); plswap(w1, w3); plswap(w4, w6); plswap(w5, w7);
      union U { unsigned u[4]; short8 s8; } A0, A1;
      A0.u[0] = w0; A0.u[1] = w1; A0.u[2] = w2; A0.u[3] = w3;
      A1.u[0] = w4; A1.u[1] = w5; A1.u[2] = w6; A1.u[3] = w7;
      pa0[ks] = A0.s8; pa1[ks] = A1.s8;
    }

    // PV from V[cur] (double-buffered -> no intra-kt barrier)
    __builtin_amdgcn_s_setprio(1);
#pragma unroll
    for (int ks = 0; ks < 2; ++ks){
#pragma unroll
      for (int dt = 0; dt < 3; ++dt){
        const int vrow = dt * 32 + q5;
        int c0 = ks * 4 + hi;
        short8 vf0 = *(const short8*)&Vs[(size_t)cur * 8192 + vrow * 64 + ((c0 ^ (vrow & 7)) * 8)];
        oacc[dt] = mfma32(pa0[ks], vf0, oacc[dt]);
        int c1 = ks * 4 + 2 + hi;
        short8 vf1 = *(const short8*)&Vs[(size_t)cur * 8192 + vrow * 64 + ((c1 ^ (vrow & 7)) * 8)];
        oacc[dt] = mfma32(pa1[ks], vf1, oacc[dt]);
      }
    }
    __builtin_amdgcn_s_setprio(0);

    if (kt == 16) break;
    BARX();
    if (kt <= 14){
      STAGE_K(cur, kt + 2);
      STAGE_V(cur, kt + 2);
      WAITV(4);                      // kt+1 K/V resident (+ stores drained); kt+2 in flight
    } else {
      WAITV(0);                      // kt == 15: K16,V16 resident
    }
    BARX();
  }

  // epilogue: D[q][d]: col = lane&31 = d, row = (r&3)+8*(r>>2)+4*hi = q
#pragma unroll
  for (int dt = 0; dt < 3; ++dt){
    const int d = dt * 32 + q5;
    if (d < 88){
#pragma unroll
      for (int r = 0; r < 16; ++r){
        int qq2 = qb0 + (r & 3) + 8 * (r >> 2) + 4 * hi;
        if (qq2 < 1025)
          AO[((size_t)b * 1025 + qq2) * E_DIM + h * 88 + d] = f2bf(oacc[dt][r]);
      }
    }
  }
}

extern "C" void kernel_launch(void* const* d_in, const int* in_sizes, int n_in,
                              void* d_out, int out_size, void* d_ws, size_t ws_size,
                              hipStream_t stream)
{
  const float* hs   = (const float*)d_in[0];
  const float* fcos = (const float*)d_in[1];
  const float* fsin = (const float*)d_in[2];
  const float* q_w  = (const float*)d_in[3];
  const float* q_b  = (const float*)d_in[4];
  const float* k_w  = (const float*)d_in[5];
  const float* k_b  = (const float*)d_in[6];
  const float* v_w  = (const float*)d_in[7];
  const float* v_b  = (const float*)d_in[8];
  const float* o_w  = (const float*)d_in[9];
  const float* o_b  = (const float*)d_in[10];
  float* out0 = (float*)d_out;
  float* attn = out0 + (size_t)B_BATCH * S_SEQ * E_DIM;

  char* ws = (char*)d_ws;
  size_t off = 0;
  auto take = [&](size_t bytes){
    char* p = ws + off; off += (bytes + 255) & ~(size_t)255; return p;
  };
  u16* Xb   = (u16*)take((size_t)M_PAD * E_DIM * 2);
  u16* Wqkv = (u16*)take((size_t)N_QKV * E_DIM * 2);
  u16* Wo   = (u16*)take((size_t)E_DIM * E_DIM * 2);
  u16* Qb   = (u16*)take((size_t)128 * S_PAD * D_PAD * 2);
  u16* Kb   = (u16*)take((size_t)128 * S_PAD * D_PAD * 2);
  u16* Vtb  = (u16*)take((size_t)128 * D_PAD * S_PAD * 2);
  u16* AO   = (u16*)take((size_t)M_PAD * E_DIM * 2);

  cvt_kernel<<<(1443200 + 255) / 256, 256, 0, stream>>>(hs, Xb, 1443200);
  cvt3_kernel<<<dim3(968, 3), 256, 0, stream>>>(q_w, k_w, v_w, Wqkv, 247808);
  cvt_kernel<<<968, 256, 0, stream>>>(o_w, Wo, 247808);
  zero_pads_kernel<<<10400, 256, 0, stream>>>(Qb, Kb, Vtb);

  gemm_bt<0><<<dim3(33, 65), 256, 0, stream>>>(Xb, Wqkv, q_b, k_b, v_b,
                                               Qb, Kb, Vtb, nullptr, fcos, fsin);

  attn_kernel<<<dim3(5, 128), 512, 0, stream>>>(Qb, Kb, Vtb, attn, AO);

  gemm_bt<1><<<dim3(11, 65), 256, 0, stream>>>(AO, Wo, o_b, o_b, o_b,
                                               nullptr, nullptr, nullptr, out0, fcos, fsin);
}

// Round 8
// 557.157 us; speedup vs baseline: 1.6956x; 1.0074x over previous
//
#include <hip/hip_runtime.h>

typedef unsigned short u16;
typedef __attribute__((ext_vector_type(8))) short short8;
typedef __attribute__((ext_vector_type(4))) float f32x4;
typedef __attribute__((ext_vector_type(16))) float f32x16;

#define E_DIM 1408
#define H_HEADS 16
#define S_SEQ 1025
#define B_BATCH 8
#define S_PAD 1088      // 17*64
#define D_PAD 128
#define M_ROWS 8200     // B*S
#define M_PAD 8320      // 65*128
#define N_QKV 4224

struct __attribute__((packed, aligned(4))) f4u { float x, y, z, w; };

__device__ __forceinline__ u16 f2bf(float f){
  union { float f; unsigned u; } x; x.f = f;
  unsigned r = x.u + 0x7fffu + ((x.u >> 16) & 1u);
  return (u16)(r >> 16);
}

__device__ __forceinline__ void gload16(const void* g, void* l){
  __builtin_amdgcn_global_load_lds(
      (const __attribute__((address_space(1))) void*)g,
      (__attribute__((address_space(3))) void*)l, 16, 0, 0);
}

__device__ __forceinline__ f32x4 mfma16(short8 a, short8 b, f32x4 c){
  return __builtin_amdgcn_mfma_f32_16x16x32_bf16(a, b, c, 0, 0, 0);
}
__device__ __forceinline__ f32x16 mfma32(short8 a, short8 b, f32x16 c){
  return __builtin_amdgcn_mfma_f32_32x32x16_bf16(a, b, c, 0, 0, 0);
}

__device__ __forceinline__ unsigned cvtpk(float a, float b){
  unsigned r;
  asm("v_cvt_pk_bf16_f32 %0, %1, %2" : "=v"(r) : "v"(a), "v"(b));
  return r;
}
__device__ __forceinline__ void plswap(unsigned &a, unsigned &b){
  asm("v_permlane32_swap_b32 %0, %1" : "+v"(a), "+v"(b));
}

#define BARX() { asm volatile("" ::: "memory"); __builtin_amdgcn_s_barrier(); asm volatile("" ::: "memory"); }
#define WAITV(n) asm volatile("s_waitcnt vmcnt(" #n ")" ::: "memory")

// ---------------- fp32 -> bf16 convert (8 elems/thread) ----------------
__global__ __launch_bounds__(256) void cvt_kernel(const float* __restrict__ src,
                                                  u16* __restrict__ dst, int n8){
  int i = blockIdx.x * 256 + threadIdx.x;
  if (i >= n8) return;
  const float4* s4 = (const float4*)src;
  float4 a = s4[2*i], b = s4[2*i+1];
  union { u16 u[8]; short8 v; } o;
  o.u[0]=f2bf(a.x); o.u[1]=f2bf(a.y); o.u[2]=f2bf(a.z); o.u[3]=f2bf(a.w);
  o.u[4]=f2bf(b.x); o.u[5]=f2bf(b.y); o.u[6]=f2bf(b.z); o.u[7]=f2bf(b.w);
  ((short8*)dst)[i] = o.v;
}

// 3 equal-size weight matrices (q,k,v) in one dispatch (grid.y = 3)
__global__ __launch_bounds__(256) void cvt3_kernel(const float* __restrict__ s0,
                                                   const float* __restrict__ s1,
                                                   const float* __restrict__ s2,
                                                   u16* __restrict__ dst, int n8){
  int i = blockIdx.x * 256 + threadIdx.x;
  if (i >= n8) return;
  const float* src = (blockIdx.y == 0) ? s0 : (blockIdx.y == 1) ? s1 : s2;
  u16* d = dst + (size_t)blockIdx.y * n8 * 8;
  const float4* s4 = (const float4*)src;
  float4 a = s4[2*i], b = s4[2*i+1];
  union { u16 u[8]; short8 v; } o;
  o.u[0]=f2bf(a.x); o.u[1]=f2bf(a.y); o.u[2]=f2bf(a.z); o.u[3]=f2bf(a.w);
  o.u[4]=f2bf(b.x); o.u[5]=f2bf(b.y); o.u[6]=f2bf(b.z); o.u[7]=f2bf(b.w);
  ((short8*)d)[i] = o.v;
}

// ---------------- zero hazardous pad regions ----------------
__global__ __launch_bounds__(256) void zero_pads_kernel(u16* __restrict__ Q,
                                                        u16* __restrict__ K,
                                                        u16* __restrict__ Vt){
  int i = blockIdx.x * 256 + threadIdx.x;
  const int n1 = 128 * S_PAD * 8;
  const int n2 = 128 * 63 * 96;
  const int n3 = 128 * 96 * 63;
  if (i < n1){
    int d = 88 + (i & 7); int t = i >> 3;
    int s = t % S_PAD; int bh = t / S_PAD;
    size_t o = ((size_t)bh * S_PAD + s) * D_PAD + d;
    Q[o] = 0; K[o] = 0;
  } else if (i < n1 + n2){
    int j = i - n1;
    int d = j % 96; int t = j / 96;
    int s = 1025 + t % 63; int bh = t / 63;
    size_t o = ((size_t)bh * S_PAD + s) * D_PAD + d;
    Q[o] = 0; K[o] = 0;
  } else if (i < n1 + n2 + n3){
    int j = i - n1 - n2;
    int d = j % 96; int t = j / 96;
    int sp = 1025 + t % 63; int bh = t / 63;
    Vt[((size_t)bh * D_PAD + d) * S_PAD + sp] = 0;
  }
}

// ---------------- GEMM  C = A @ W^T + bias (m97-style 128x128) ----------------
// MODE 0: fused Q,K (bx/11 = region): RoPE epilogue (Q pre-scaled)
// MODE 1: fp32 out (O-projection)
// MODE 2: V^T via swapped operands: A = Wv (rows = out-dim jl), W = X (rows = s)
//         C[jl][s] stored to Vt coalesced along s.
template<int MODE>
__global__ __launch_bounds__(256) void gemm_bt(
    const u16* __restrict__ A, const u16* __restrict__ W,
    const float* __restrict__ b_q, const float* __restrict__ b_k,
    const float* __restrict__ b_v,
    u16* __restrict__ Qb, u16* __restrict__ Kb, u16* __restrict__ Vtb,
    float* __restrict__ outF,
    const float* __restrict__ fcos, const float* __restrict__ fsin)
{
  __shared__ u16 As[128*32];
  __shared__ u16 Bs[128*32];
  const int tid = threadIdx.x;
  const int lane = tid & 63, wid = tid >> 6;
  const int cl = lane & 15, grp = lane >> 4;

  // bijective XCD swizzle (m204)
  const int nwg = (int)(gridDim.x * gridDim.y);
  const int orig = blockIdx.x + gridDim.x * blockIdx.y;
  const int qq = nwg >> 3, rr = nwg & 7;
  const int xcd = orig & 7, kk = orig >> 3;
  const int wg = (xcd < rr ? xcd * (qq + 1) : rr * (qq + 1) + (xcd - rr) * qq) + kk;
  const int bx = wg % (int)gridDim.x, by = wg / (int)gridDim.x;

  const int n0 = bx * 128, m0 = by * 128;
  const int region = (MODE == 0) ? (bx / 11) : 0;
  const int wm = (wid >> 1) * 64, wn = (wid & 1) * 64;
  f32x4 acc[4][4] = {};

  for (int k0 = 0; k0 < E_DIM; k0 += 32){
    __syncthreads();
#pragma unroll
    for (int rd = 0; rd < 2; ++rd){
      int G = rd * 256 + tid;
      int row = G >> 2, cg = G & 3;
      gload16(A + (size_t)(m0 + row) * E_DIM + k0 + cg * 8, (char*)As + (size_t)G * 16);
      gload16(W + (size_t)(n0 + row) * E_DIM + k0 + cg * 8, (char*)Bs + (size_t)G * 16);
    }
    __syncthreads();
    short8 av[4], bv[4];
#pragma unroll
    for (int i = 0; i < 4; ++i) av[i] = *(const short8*)&As[(wm + i*16 + cl)*32 + grp*8];
#pragma unroll
    for (int j = 0; j < 4; ++j) bv[j] = *(const short8*)&Bs[(wn + j*16 + cl)*32 + grp*8];
    __builtin_amdgcn_s_setprio(1);
#pragma unroll
    for (int i = 0; i < 4; ++i)
#pragma unroll
      for (int j = 0; j < 4; ++j)
        acc[i][j] = mfma16(av[i], bv[j], acc[i][j]);
    __builtin_amdgcn_s_setprio(0);
  }

  const float QSCALE = 0.15379181f;   // log2(e)/sqrt(88), folded into Q

  if (MODE == 2){
    // C[jl = m-axis][s = n-axis] -> Vt[(bb*16+hh)*128+dd][spos], coalesced in s
#pragma unroll
    for (int j = 0; j < 4; ++j){
      const int scol = n0 + wn + j*16 + cl;        // global s-row index
      const int bb = scol / 1025;
      const int spos = scol - bb * 1025;
      const bool ok = (scol < M_ROWS);
#pragma unroll
      for (int i = 0; i < 4; ++i){
#pragma unroll
        for (int r = 0; r < 4; ++r){
          const int jl = m0 + wm + i*16 + grp*4 + r;
          const int hh = jl / 88;
          const int dd = jl - hh * 88;
          float v = acc[i][j][r] + b_v[jl];
          if (ok)
            Vtb[(((size_t)(bb * 16 + hh)) * D_PAD + dd) * S_PAD + spos] = f2bf(v);
        }
      }
    }
    return;
  }

  const float* bias = (MODE == 1) ? b_q : (region == 0 ? b_q : b_k);

#pragma unroll
  for (int i = 0; i < 4; ++i){
#pragma unroll
    for (int j = 0; j < 4; ++j){
      const int jcol = n0 + wn + j*16 + cl;
      const int jl = jcol - region * E_DIM;
      const float bsv = bias[jl];
      const int hh = jl / 88;
      const int dd = jl - hh * 88;
#pragma unroll
      for (int r = 0; r < 4; ++r){
        const int rrow = m0 + wm + i*16 + grp*4 + r;
        float v = acc[i][j][r] + bsv;
        if (MODE == 0){
          float other = __shfl_xor(v, 1);
          int bb = rrow / 1025;
          int spos = rrow - bb * 1025;
          int pp = dd >> 1;
          float c = fcos[spos * 44 + pp];
          float s = fsin[spos * 44 + pp];
          float o = fmaf(v, c, (jl & 1) ? (other * s) : -(other * s));
          if (region == 0) o *= QSCALE;
          if (rrow < M_ROWS){
            size_t dst = (((size_t)(bb * 16 + hh)) * S_PAD + spos) * D_PAD + dd;
            (region ? Kb : Qb)[dst] = f2bf(o);
          }
        } else {
          if (rrow < M_ROWS) outF[(size_t)rrow * E_DIM + jcol] = v;
        }
      }
    }
  }
}

// ---------------- fused attention (mfma 32x32x16, counted vmcnt) ----------------
// block = 256 thr (4 waves), q-tile 128; LDS 44KB -> 3 blocks/CU.
// Per-wave vmem counts: STAGE_K = 4 instr, STAGE_V = 3, attn-stores = 8 (exec-full
// via dump-clamp). Waits are exact: nothing drains to 0 until the final tile.
#define STAGE_K(buf, kt)                                                        \
  {                                                                             \
    _Pragma("unroll")                                                           \
    for (int rd = 0; rd < 4; ++rd){                                             \
      int G = rd * 256 + tid;                                                   \
      int row = G >> 4, c = G & 15;                                             \
      gload16(Kg + (size_t)((kt) * 64 + row) * 128 + ((c ^ (row & 15)) * 8),    \
              (char*)&Ks[buf][0] + (size_t)G * 16);                             \
    }                                                                           \
  }

#define STAGE_V(kt)                                                             \
  {                                                                             \
    _Pragma("unroll")                                                           \
    for (int rd = 0; rd < 3; ++rd){                                             \
      int G = rd * 256 + tid;                                                   \
      int row = G >> 3, c = G & 7;                                              \
      gload16(Vg + (size_t)row * S_PAD + (kt) * 64 + ((c ^ (row & 7)) * 8),     \
              (char*)Vs + (size_t)G * 16);                                      \
    }                                                                           \
  }

__global__ __launch_bounds__(256, 3) void attn_kernel(
    const u16* __restrict__ Qb, const u16* __restrict__ Kb,
    const u16* __restrict__ Vtb, float* __restrict__ attn,
    u16* __restrict__ AO, float* __restrict__ dumpf)
{
  __shared__ u16 Ks[2][64 * 128];    // 32 KB, double-buffered
  __shared__ u16 Vs[96 * 64];        // 12 KB, single-buffered
  const int tid = threadIdx.x, wid = tid >> 6, lane = tid & 63;
  const int q5 = lane & 31, hi = lane >> 5;
  int lin = blockIdx.x + gridDim.x * blockIdx.y;     // 9*128 = 1152 blocks
  lin = (lin & 7) * 144 + (lin >> 3);                // XCD-contiguous (1152 = 8*144)
  const int qt = lin % 9, bh = lin / 9;
  const int b = bh >> 4, h = bh & 15;
  const u16* __restrict__ Qg = Qb + (size_t)bh * S_PAD * 128;
  const u16* __restrict__ Kg = Kb + (size_t)bh * S_PAD * 128;
  const u16* __restrict__ Vg = Vtb + (size_t)bh * 128 * S_PAD;
  const int qb0 = qt * 128 + wid * 32;
  const int qrow = qb0 + q5;
  const int qrowc = (qrow < S_PAD) ? qrow : (S_PAD - 1);

  short8 qf[6];
#pragma unroll
  for (int ds = 0; ds < 6; ++ds)
    qf[ds] = *(const short8*)&Qg[(size_t)qrowc * 128 + ds * 16 + hi * 8];

  // ---- pass 1: row sums of 2^sc (pad K rows give 2^0 = 1 -> subtract 63) ----
  float l0 = 0.f, l1 = 0.f, l2 = 0.f, l3 = 0.f;
  STAGE_K(0, 0);                     // +4
  for (int kt = 0; kt < 17; ++kt){
    const int cur = kt & 1;
    if (kt < 16){
      STAGE_K(cur ^ 1, kt + 1);      // outstanding: K(kt)4 + K(kt+1)4
      WAITV(4);                      // K(kt) resident; K(kt+1) flies
    } else {
      WAITV(0);
    }
    BARX();
#pragma unroll
    for (int ks = 0; ks < 2; ++ks){
      f32x16 sc = {};
      const int krow = ks * 32 + q5;
      __builtin_amdgcn_s_setprio(1);
#pragma unroll
      for (int ds = 0; ds < 6; ++ds){
        int c = ds * 2 + hi;
        short8 kf = *(const short8*)&Ks[cur][krow * 128 + ((c ^ (krow & 15)) * 8)];
        sc = mfma32(kf, qf[ds], sc);
      }
      __builtin_amdgcn_s_setprio(0);
#pragma unroll
      for (int r = 0; r < 16; r += 4){
        l0 += __builtin_amdgcn_exp2f(sc[r]);
        l1 += __builtin_amdgcn_exp2f(sc[r+1]);
        l2 += __builtin_amdgcn_exp2f(sc[r+2]);
        l3 += __builtin_amdgcn_exp2f(sc[r+3]);
      }
    }
    BARX();                          // Ks[cur] consumed before restage at kt+1
  }
  float l = (l0 + l1) + (l2 + l3);
  l += __shfl_xor(l, 32);
  l -= 63.0f;                        // exact pad correction
  const float lg2l = __builtin_amdgcn_logf(l);

  // ---- pass 2: p = 2^(sc - lg2l); write attn; PV ----
  f32x16 oacc[3] = {};
  STAGE_K(0, 0);                     // +4
  STAGE_V(0);                        // +3
  for (int kt = 0; kt < 17; ++kt){
    const int cur = kt & 1;
    if (kt < 16) STAGE_K(cur ^ 1, kt + 1);           // +4
    // top wait: retire K(kt); keep st(kt-1)(8) + V(kt)(3) + K(kt+1)(4) in flight
    if (kt == 0)      { WAITV(7); }                  // [K0:4,V0:3,K1:4] -> 7
    else if (kt < 16) { WAITV(15); }                 // [K:4,st:8,V:3,K':4] -> 15
    else              { WAITV(11); }                 // [K16:4,st15:8,V16:3] -> 11
    BARX();
    short8 pa0[2], pa1[2];
#pragma unroll
    for (int ks = 0; ks < 2; ++ks){
      f32x16 sc = {};
      const int krow = ks * 32 + q5;
      __builtin_amdgcn_s_setprio(1);
#pragma unroll
      for (int ds = 0; ds < 6; ++ds){
        int c = ds * 2 + hi;
        short8 kf = *(const short8*)&Ks[cur][krow * 128 + ((c ^ (krow & 15)) * 8)];
        sc = mfma32(kf, qf[ds], sc);
      }
      __builtin_amdgcn_s_setprio(0);
#pragma unroll
      for (int r = 0; r < 16; ++r) sc[r] = __builtin_amdgcn_exp2f(sc[r] - lg2l);

      // attn stores: EXEC-FULL (invalid lanes -> dump) so vmcnt counts are exact
      if (kt < 16){
        float* arow = (qrow < 1025)
          ? attn + ((size_t)bh * 1025 + qrow) * 1025 + kt * 64 + ks * 32 + 4 * hi
          : dumpf + tid * 16;
#pragma unroll
        for (int g = 0; g < 4; ++g){
          f4u w4 = { sc[4*g], sc[4*g+1], sc[4*g+2], sc[4*g+3] };
          *(f4u*)(arow + 8 * g) = w4;
        }
      } else {
#pragma unroll
        for (int r = 0; r < 16; ++r){
          int kabs = 1024 + ks * 32 + (r & 3) + 8 * (r >> 2) + 4 * hi;
          float* ad = (qrow < 1025 && kabs < 1025)
            ? attn + ((size_t)bh * 1025 + qrow) * 1025 + kabs
            : dumpf + tid;
          *ad = sc[r];
        }
      }

      // P -> bf16 A-fragments: 8 cvt_pk + 4 permlane32_swap
      unsigned w0 = cvtpk(sc[0],  sc[1]),  w1 = cvtpk(sc[2],  sc[3]);
      unsigned w2 = cvtpk(sc[4],  sc[5]),  w3 = cvtpk(sc[6],  sc[7]);
      unsigned w4 = cvtpk(sc[8],  sc[9]),  w5 = cvtpk(sc[10], sc[11]);
      unsigned w6 = cvtpk(sc[12], sc[13]), w7 = cvtpk(sc[14], sc[15]);
      plswap(w0, w2); plswap(w1, w3); plswap(w4, w6); plswap(w5, w7);
      union U { unsigned u[4]; short8 s8; } A0, A1;
      A0.u[0] = w0; A0.u[1] = w1; A0.u[2] = w2; A0.u[3] = w3;
      A1.u[0] = w4; A1.u[1] = w5; A1.u[2] = w6; A1.u[3] = w7;
      pa0[ks] = A0.s8; pa1[ks] = A1.s8;
    }

    // mid wait: retire st(kt-1)+V(kt); keep K(kt+1)(4)+st(kt)(8) in flight
    if (kt < 16) { WAITV(12); } else { WAITV(0); }
    BARX();
    __builtin_amdgcn_s_setprio(1);
#pragma unroll
    for (int ks = 0; ks < 2; ++ks){
#pragma unroll
      for (int dt = 0; dt < 3; ++dt){
        const int vrow = dt * 32 + q5;
        int c0 = ks * 4 + hi;
        short8 vf0 = *(const short8*)&Vs[vrow * 64 + ((c0 ^ (vrow & 7)) * 8)];
        oacc[dt] = mfma32(pa0[ks], vf0, oacc[dt]);
        int c1 = ks * 4 + 2 + hi;
        short8 vf1 = *(const short8*)&Vs[vrow * 64 + ((c1 ^ (vrow & 7)) * 8)];
        oacc[dt] = mfma32(pa1[ks], vf1, oacc[dt]);
      }
    }
    __builtin_amdgcn_s_setprio(0);
    BARX();                          // Vs consumed
    if (kt < 16) STAGE_V(kt + 1);    // +3, overlaps next QK
  }

  // epilogue: D[q][d]: col = lane&31 = d, row = (r&3)+8*(r>>2)+4*hi = q
#pragma unroll
  for (int dt = 0; dt < 3; ++dt){
    const int d = dt * 32 + q5;
    if (d < 88){
#pragma unroll
      for (int r = 0; r < 16; ++r){
        int qq2 = qb0 + (r & 3) + 8 * (r >> 2) + 4 * hi;
        if (qq2 < 1025)
          AO[((size_t)b * 1025 + qq2) * E_DIM + h * 88 + d] = f2bf(oacc[dt][r]);
      }
    }
  }
}

extern "C" void kernel_launch(void* const* d_in, const int* in_sizes, int n_in,
                              void* d_out, int out_size, void* d_ws, size_t ws_size,
                              hipStream_t stream)
{
  const float* hs   = (const float*)d_in[0];
  const float* fcos = (const float*)d_in[1];
  const float* fsin = (const float*)d_in[2];
  const float* q_w  = (const float*)d_in[3];
  const float* q_b  = (const float*)d_in[4];
  const float* k_w  = (const float*)d_in[5];
  const float* k_b  = (const float*)d_in[6];
  const float* v_w  = (const float*)d_in[7];
  const float* v_b  = (const float*)d_in[8];
  const float* o_w  = (const float*)d_in[9];
  const float* o_b  = (const float*)d_in[10];
  float* out0 = (float*)d_out;
  float* attn = out0 + (size_t)B_BATCH * S_SEQ * E_DIM;

  char* ws = (char*)d_ws;
  size_t off = 0;
  auto take = [&](size_t bytes){
    char* p = ws + off; off += (bytes + 255) & ~(size_t)255; return p;
  };
  u16* Xb   = (u16*)take((size_t)M_PAD * E_DIM * 2);
  u16* Wqkv = (u16*)take((size_t)N_QKV * E_DIM * 2);
  u16* Wo   = (u16*)take((size_t)E_DIM * E_DIM * 2);
  u16* Qb   = (u16*)take((size_t)128 * S_PAD * D_PAD * 2);
  u16* Kb   = (u16*)take((size_t)128 * S_PAD * D_PAD * 2);
  u16* Vtb  = (u16*)take((size_t)128 * D_PAD * S_PAD * 2);
  u16* AO   = (u16*)take((size_t)M_PAD * E_DIM * 2);
  float* dumpf = (float*)take(65536);

  cvt_kernel<<<(1443200 + 255) / 256, 256, 0, stream>>>(hs, Xb, 1443200);
  cvt3_kernel<<<dim3(968, 3), 256, 0, stream>>>(q_w, k_w, v_w, Wqkv, 247808);
  cvt_kernel<<<968, 256, 0, stream>>>(o_w, Wo, 247808);
  zero_pads_kernel<<<10400, 256, 0, stream>>>(Qb, Kb, Vtb);

  // Q,K: C = X @ W^T with RoPE epilogue
  gemm_bt<0><<<dim3(22, 65), 256, 0, stream>>>(Xb, Wqkv, q_b, k_b, v_b,
                                               Qb, Kb, Vtb, nullptr, fcos, fsin);
  // V^T: C = Wv @ X^T, stores coalesced along s
  gemm_bt<2><<<dim3(65, 11), 256, 0, stream>>>(Wqkv + 2 * (size_t)E_DIM * E_DIM, Xb,
                                               q_b, k_b, v_b,
                                               Qb, Kb, Vtb, nullptr, fcos, fsin);

  attn_kernel<<<dim3(9, 128), 256, 0, stream>>>(Qb, Kb, Vtb, attn, AO, dumpf);

  gemm_bt<1><<<dim3(11, 65), 256, 0, stream>>>(AO, Wo, o_b, o_b, o_b,
                                               nullptr, nullptr, nullptr, out0, fcos, fsin);
}